// Round 14
// baseline (34.263 us; speedup 1.0000x reference)
//
#include <hip/hip_runtime.h>
#include <math.h>

typedef __attribute__((ext_vector_type(8))) short short8;
typedef __attribute__((ext_vector_type(4))) float f32x4;

namespace {
constexpr int NEL   = 4;
constexpr int NEXP  = 16;
constexpr int Bb    = 128;
constexpr int Aa    = 128;
constexpr int Cc    = 256;
constexpr int FATOM = 176;
constexpr int FPAIR = 32;
constexpr int FIN   = 384;
constexpr int HH1   = 128;
constexpr int HH2   = 96;
constexpr int NP    = Bb * Cc;                // 32768
constexpr int NA    = Bb * Aa;                // 16384
constexpr int BUCKET_CAP = 4096;

// ws int offsets
constexpr int WS_COUNTS = 0;                  // 16 ints
constexpr int WS_B2     = 64;                 // int4[16*4096]
constexpr int WS_SHORTS = 64 + NEXP * BUCKET_CAP * 4;

// per-expert packed weights (bf16): W1 [12][128][32] | W2 [4][96][32]
constexpr int W2_OFF = 12 * HH1 * 32;         // 49152 shorts
constexpr int WPK_E  = W2_OFF + 4 * HH2 * 32; // 61440 shorts (120 KB)
constexpr int WPK_N  = NEXP * WPK_E;

constexpr int SYM_N  = NA * FATOM;            // 2,883,584
constexpr int PAIR_N = NP * FPAIR;            // 1,048,576

// fused prep grid: cvt_x | W1-pack | W2-pack | idx
constexpr int CVT_BLOCKS = (SYM_N / 4 + PAIR_N / 4) / 256;  // 3840
constexpr int W1_BLOCKS  = 768;
constexpr int W2_BLOCKS  = 192;
constexpr int IDX_BLOCKS = NP / 256;                        // 128
constexpr int W1_BASE  = CVT_BLOCKS;
constexpr int W2_BASE  = W1_BASE + W1_BLOCKS;
constexpr int IDX_BASE = W2_BASE + W2_BLOCKS;
constexpr int PREP_GRID = IDX_BASE + IDX_BLOCKS;            // 4928
}

__device__ inline short f2bf(float f) {
    unsigned u = __builtin_bit_cast(unsigned, f);
    unsigned r = (u + 0x7FFFu + ((u >> 16) & 1u)) >> 16;
    return (short)r;
}
__device__ inline float celu1(float v) {
    return v > 0.f ? v : (__expf(v) - 1.0f);
}
// async global->LDS, 16B per lane (no VGPR round trip)
__device__ inline void gl_lds16(const short* g, short* l) {
    __builtin_amdgcn_global_load_lds(
        (const __attribute__((address_space(1))) void*)g,
        (__attribute__((address_space(3))) void*)l, 16, 0, 0);
}

// ---- fused prep: cvt_x | W1 pack | W2 pack | expert index -> bucket2 ----
__global__ __launch_bounds__(256) void k_prep(
    const float* __restrict__ sym, const float* __restrict__ pairf,
    short* __restrict__ symb, short* __restrict__ pairfb,
    const float* __restrict__ W1, const float* __restrict__ W2,
    short* __restrict__ wpk,
    const int* __restrict__ conn, const int* __restrict__ elements,
    int* __restrict__ counts, int4* __restrict__ bucket2,
    float* __restrict__ out)
{
    __shared__ float T[32][33];
    __shared__ int sh_cnt[NEXP], sh_base[NEXP];

    int bid = blockIdx.x;
    int t = threadIdx.x;

    if (bid < CVT_BLOCKS) {
        int i = bid * 256 + t;
        constexpr int NS4 = SYM_N / 4;
        const float4* src; short* dst; int j;
        if (i < NS4) { src = (const float4*)sym;   dst = symb;   j = i; }
        else         { src = (const float4*)pairf; dst = pairfb; j = i - NS4; }
        float4 v = src[j];
        short4 o;
        o.x = f2bf(v.x); o.y = f2bf(v.y); o.z = f2bf(v.z); o.w = f2bf(v.w);
        *(short4*)(dst + 4 * (size_t)j) = o;
    } else if (bid < IDX_BASE) {
        const float* src; short* dst; int N, k0, n0;
        if (bid < W2_BASE) {
            int b1i = bid - W1_BASE;
            int e = b1i / 48, tl = b1i % 48;
            N = HH1; k0 = (tl % 12) * 32; n0 = (tl / 12) * 32;
            src = W1 + (size_t)e * FIN * HH1;
            dst = wpk + (size_t)e * WPK_E;
        } else {
            int b2i = bid - W2_BASE;
            int e = b2i / 12, tl = b2i % 12;
            N = HH2; k0 = (tl % 4) * 32; n0 = (tl / 4) * 32;
            src = W2 + (size_t)e * HH1 * HH2;
            dst = wpk + (size_t)e * WPK_E + W2_OFF;
        }
        int tx = t & 31, ty = t >> 5;
        int ks = k0 >> 5;
#pragma unroll
        for (int j = 0; j < 4; ++j) {
            int r = ty + 8 * j;
            T[r][tx] = src[(size_t)(k0 + r) * N + n0 + tx];
        }
        __syncthreads();
#pragma unroll
        for (int j = 0; j < 4; ++j) {
            int n = n0 + ty + 8 * j;
            dst[(size_t)(ks * N + n) * 32 + tx] = f2bf(T[tx][ty + 8 * j]);
        }
    } else {
        int p = (bid - IDX_BASE) * 256 + t;
        if (t < NEXP) sh_cnt[t] = 0;
        __syncthreads();
        int e = -1, r = 0, i0 = 0, i1 = 0;
        {
            int c0 = conn[2 * p], c1 = conn[2 * p + 1];
            if (c0 != -1) {
                int b = p / Cc;
                i0 = b * Aa + c0; if (i0 < 0) i0 += NA;
                i1 = b * Aa + c1; if (i1 < 0) i1 += NA;
                e = elements[i0] * NEL + elements[i1];
            }
            if (e < 0 || e >= NEXP) {
                out[2 * p] = 0.f; out[2 * p + 1] = 0.f;
                e = -1;
            } else {
                r = atomicAdd(&sh_cnt[e], 1);
            }
        }
        __syncthreads();
        if (t < NEXP) sh_base[t] = (sh_cnt[t] > 0) ? atomicAdd(&counts[t], sh_cnt[t]) : 0;
        __syncthreads();
        if (e >= 0) {
            int pos = sh_base[e] + r;
            if (pos < BUCKET_CAP) {
                int4 rec; rec.x = p; rec.y = i0; rec.z = i1; rec.w = 0;
                bucket2[e * BUCKET_CAP + pos] = rec;
            }
        }
    }
}

// A-fragment address for K-step ks (ks uniform; lane-dep only at ks==5)
__device__ inline const short* aptr(int ks, const short* fa, const short* fb,
                                    const short* pf, int lg)
{
    if (ks < 5)  return fa + 32 * ks + 8 * lg;
    if (ks == 5) return (lg < 2 ? fa + 160 : fb - 16) + 8 * lg;
    if (ks < 11) return fb + 16 + 32 * (ks - 6) + 8 * lg;
    return pf + 8 * lg;
}

// epilogue: H1(celu,swizzle-store) -> L2 MFMA -> L3 fma -> out, one 16-pair group
#define EPILOG(ACC, II, PP) do {                                              \
    _Pragma("unroll")                                                         \
    for (int j = 0; j < 8; ++j)                                               \
        _Pragma("unroll")                                                     \
        for (int r2 = 0; r2 < 4; ++r2) {                                      \
            int m = 4 * lg + r2;                                              \
            int n = 16 * j + lr;                                              \
            h1w[m * HH1 + (((n >> 3) ^ (m & 7)) << 3) + (n & 7)] = f2bf(celu1(ACC[j][r2])); \
        }                                                                     \
    asm volatile("s_waitcnt lgkmcnt(0)" ::: "memory");                        \
    __builtin_amdgcn_sched_barrier(0);                                        \
    int mx = lr & 7;                                                          \
    short8 bh0 = *(const short8*)&h1w[lr * HH1 + (((0 + lg) ^ mx) << 3)];     \
    short8 bh1 = *(const short8*)&h1w[lr * HH1 + (((4 + lg) ^ mx) << 3)];     \
    short8 bh2 = *(const short8*)&h1w[lr * HH1 + (((8 + lg) ^ mx) << 3)];     \
    short8 bh3 = *(const short8*)&h1w[lr * HH1 + (((12 + lg) ^ mx) << 3)];    \
    float s0 = 0.f, s1 = 0.f;                                                 \
    _Pragma("unroll")                                                         \
    for (int t6 = 0; t6 < 6; ++t6) {                                          \
        int n2b = 16 * t6 + 4 * lg;                                           \
        float4 bb4 = *(const float4*)&b2[e * HH2 + n2b];                      \
        f32x4 a2c;                                                            \
        a2c[0] = bb4.x; a2c[1] = bb4.y; a2c[2] = bb4.z; a2c[3] = bb4.w;       \
        short8 aw0 = *(const short8*)&Wlds[W2_OFF + (0 * HH2 + 16 * t6 + lr) * 32 + 8 * lg]; \
        a2c = __builtin_amdgcn_mfma_f32_16x16x32_bf16(aw0, bh0, a2c, 0, 0, 0); \
        short8 aw1 = *(const short8*)&Wlds[W2_OFF + (1 * HH2 + 16 * t6 + lr) * 32 + 8 * lg]; \
        a2c = __builtin_amdgcn_mfma_f32_16x16x32_bf16(aw1, bh1, a2c, 0, 0, 0); \
        short8 aw2 = *(const short8*)&Wlds[W2_OFF + (2 * HH2 + 16 * t6 + lr) * 32 + 8 * lg]; \
        a2c = __builtin_amdgcn_mfma_f32_16x16x32_bf16(aw2, bh2, a2c, 0, 0, 0); \
        short8 aw3 = *(const short8*)&Wlds[W2_OFF + (3 * HH2 + 16 * t6 + lr) * 32 + 8 * lg]; \
        a2c = __builtin_amdgcn_mfma_f32_16x16x32_bf16(aw3, bh3, a2c, 0, 0, 0); \
        float4 w3a = *(const float4*)&W3[(size_t)(e * HH2 + n2b) * 2];        \
        float4 w3b = *(const float4*)&W3[(size_t)(e * HH2 + n2b) * 2 + 4];    \
        float h0 = celu1(a2c[0]), h1c = celu1(a2c[1]), h2 = celu1(a2c[2]), h3 = celu1(a2c[3]); \
        s0 = fmaf(h0, w3a.x, fmaf(h1c, w3a.z, fmaf(h2, w3b.x, fmaf(h3, w3b.z, s0)))); \
        s1 = fmaf(h0, w3a.y, fmaf(h1c, w3a.w, fmaf(h2, w3b.y, fmaf(h3, w3b.w, s1)))); \
    }                                                                         \
    s0 += __shfl_xor(s0, 16); s0 += __shfl_xor(s0, 32);                       \
    s1 += __shfl_xor(s1, 16); s1 += __shfl_xor(s1, 32);                       \
    if (((lane >> 4) & 3) == 0 && (II) < cnt) {                               \
        float2 o2; o2.x = s0 + b3v.x; o2.y = s1 + b3v.y;                      \
        *(float2*)(out + 2 * (size_t)(PP)) = o2;                              \
    }                                                                         \
} while (0)

// ---- MFMA MoE: M=32 tiles; async LDS staging; rolled pipelined K-loop ----
__global__ __launch_bounds__(512, 2) void k_moe(
    const int* __restrict__ counts, const int4* __restrict__ bucket2,
    const short* __restrict__ symb, const short* __restrict__ pairfb,
    const short* __restrict__ wpk,
    const float* __restrict__ b1, const float* __restrict__ b2,
    const float* __restrict__ W3, const float* __restrict__ b3,
    float* __restrict__ out)
{
    __shared__ __align__(16) short Wlds[WPK_E];     // 120 KB
    __shared__ __align__(16) short H1s[8][16 * HH1]; // 32 KB, per-wave private

    int e     = blockIdx.x & 15;
    int shard = blockIdx.x >> 4;
    int cnt = counts[e];
    if (cnt > BUCKET_CAP) cnt = BUCKET_CAP;
    int nt = (cnt + 31) >> 5;                  // <= 128

    int t = threadIdx.x;
    int w = t >> 6;
    int lane = t & 63;
    int lr = lane & 15, lg = (lane >> 4) & 3;

    const int4* b2e = bucket2 + e * BUCKET_CAP;
    const short* wsrc = wpk + (size_t)e * WPK_E;

    int tile = w * 16 + shard;
    bool active = tile < nt;

    // records (issued first; dependent chain)
    int ii0 = tile * 32 + lr;
    int ii1 = ii0 + 16;
    int cm1 = cnt > 0 ? cnt - 1 : 0;
    int4 rec0 = b2e[active ? (ii0 < cnt ? ii0 : cm1) : 0];
    int4 rec1 = b2e[active ? (ii1 < cnt ? ii1 : cm1) : 0];

    // async W staging: 15 x 16B per lane, straight into LDS (no VGPRs)
#pragma unroll
    for (int r = 0; r < 15; ++r)
        gl_lds16(wsrc + r * 4096 + t * 8, &Wlds[r * 4096 + t * 8]);

    // per-wave constants
    float b1v[8];
#pragma unroll
    for (int j = 0; j < 8; ++j) b1v[j] = b1[e * HH1 + j * 16 + lr];
    float2 b3v = ((const float2*)b3)[e];

    // region pointers + first A fragments (ks=0)
    const short* faA = symb + (size_t)(rec0.y & (NA - 1)) * FATOM;
    const short* fbA = symb + (size_t)(rec0.z & (NA - 1)) * FATOM;
    const short* pfA = pairfb + (size_t)(rec0.x & (NP - 1)) * FPAIR;
    const short* faB = symb + (size_t)(rec1.y & (NA - 1)) * FATOM;
    const short* fbB = symb + (size_t)(rec1.z & (NA - 1)) * FATOM;
    const short* pfB = pairfb + (size_t)(rec1.x & (NP - 1)) * FPAIR;
    short8 aAc = *(const short8*)aptr(0, faA, fbA, pfA, lg);
    short8 aBc = *(const short8*)aptr(0, faB, fbB, pfB, lg);

    __syncthreads();   // drains vmcnt (staging + gathers) and syncs block
    if (!active) return;

    short* h1w = &H1s[w][0];

    // ---- Layer 1: rolled K-loop, depth-1 A prefetch, W1 from LDS ----
    f32x4 acc0[8], acc1[8];
#pragma unroll
    for (int j = 0; j < 8; ++j) {
        acc0[j] = (f32x4){b1v[j], b1v[j], b1v[j], b1v[j]};
        acc1[j] = acc0[j];
    }
#pragma unroll 1
    for (int ks = 0; ks < 12; ++ks) {
        int ksn = ks < 11 ? ks + 1 : 11;
        short8 aAn = *(const short8*)aptr(ksn, faA, fbA, pfA, lg);
        short8 aBn = *(const short8*)aptr(ksn, faB, fbB, pfB, lg);
        const short* wbase = &Wlds[(ks * HH1 + lr) * 32 + 8 * lg];
#pragma unroll
        for (int j = 0; j < 8; ++j) {
            short8 bw = *(const short8*)(wbase + j * 16 * 32);
            acc0[j] = __builtin_amdgcn_mfma_f32_16x16x32_bf16(aAc, bw, acc0[j], 0, 0, 0);
            acc1[j] = __builtin_amdgcn_mfma_f32_16x16x32_bf16(aBc, bw, acc1[j], 0, 0, 0);
        }
        aAc = aAn; aBc = aBn;
    }

    // ---- two 16-pair epilogues ----
    int pp0 = rec0.x & (NP - 1);
    int pp1 = rec1.x & (NP - 1);
    EPILOG(acc0, ii0, pp0);
    EPILOG(acc1, ii1, pp1);
}

extern "C" void kernel_launch(void* const* d_in, const int* in_sizes, int n_in,
                              void* d_out, int out_size, void* d_ws, size_t ws_size,
                              hipStream_t stream)
{
    const int*   elements = (const int*)d_in[0];
    const int*   conn     = (const int*)d_in[1];
    const float* sym      = (const float*)d_in[2];
    const float* pairf    = (const float*)d_in[3];
    const float* W1       = (const float*)d_in[4];
    const float* b1       = (const float*)d_in[5];
    const float* W2       = (const float*)d_in[6];
    const float* b2       = (const float*)d_in[7];
    const float* W3       = (const float*)d_in[8];
    const float* b3       = (const float*)d_in[9];
    float* out = (float*)d_out;

    int* wsi     = (int*)d_ws;
    int* counts  = wsi + WS_COUNTS;
    int4* bucket2 = (int4*)(wsi + WS_B2);

    short* sbase  = (short*)(wsi + WS_SHORTS);
    short* wpk    = sbase;
    short* symb   = sbase + WPK_N;
    short* pairfb = sbase + WPK_N + SYM_N;

    hipMemsetAsync((void*)counts, 0, NEXP * sizeof(int), stream);

    k_prep<<<PREP_GRID, 256, 0, stream>>>(sym, pairf, symb, pairfb,
                                          W1, W2, wpk,
                                          conn, elements, counts, bucket2, out);
    k_moe<<<256, 512, 0, stream>>>(counts, bucket2, symb, pairfb, wpk,
                                   b1, b2, W3, b3, out);
}